// Round 9
// baseline (463.662 us; speedup 1.0000x reference)
//
#include <hip/hip_runtime.h>
#include <hip/hip_cooperative_groups.h>
#include <hip/hip_bf16.h>
#include <hip/hip_fp16.h>
#include <math.h>

namespace cg = cooperative_groups;

// Problem constants: B=16, L=96, H=128.
#define BB 16
#define LL 96
#define HH 128

typedef __attribute__((ext_vector_type(8))) short short8;
typedef __attribute__((ext_vector_type(4))) float f32x4;

// Only slice kh=63 of attn_conv_w matters (input height 1, SAME pad (63,64)).
// Only slice kw=63 of cvg_conv_w matters (input width 1, SAME pad (63,64)).
//
// ws layout (float units) — round-8 layout, unchanged:
#define WS_W    0              // bf16 W [i][o][e] (e pre-XOR-swizzled), 1179648 shorts
#define WS_E    589824         // 16*96*256 fp32 zero-padded enc rows [b][i][256]
#define WS_DEC  983040         // 16*128
#define WS_CVG  985088         // 16*96
#define WS_SC   986624         // 16*96
#define WS_P    988160         // fp16 partials [kc][b][o][w]: 32*16*96*128 halves

struct __align__(16) SmemM { short A[LL * HH]; float E[256]; };   // 25.6 KB (phase 2)
struct SmemP { float hid[HH]; float cov[LL]; };                   // phase 1
struct SmemR { float r2[2]; };                                    // phase 3
struct SmemF { float sc[LL]; float at[LL]; };                     // phase 4
union __align__(16) Smem { SmemM m; SmemP p; SmemR r; SmemF f; };

__global__ __launch_bounds__(256, 2) void fused_kernel(
        const float* __restrict__ hidden,
        const float* __restrict__ enc,
        const float* __restrict__ coverage,
        const float* __restrict__ attn_w,
        const float* __restrict__ attn_b,
        const float* __restrict__ cvg_w,
        const float* __restrict__ cvg_b,
        const float* __restrict__ dec_w,
        const float* __restrict__ dec_b,
        const float* __restrict__ vvec,
        float* __restrict__ ws,
        float* __restrict__ out) {
    __shared__ Smem sh;
    const int bid = blockIdx.x;   // 0..511
    const int tid = threadIdx.x;  // 0..255

    // ================= phase 1: prep (round-8 bodies, rebalanced) =================
    if (bid < 16) {   // stage hid/cov for dec/cvg piggyback
        if (tid < HH) sh.p.hid[tid] = hidden[bid * HH + tid];
        if (tid < LL) sh.p.cov[tid] = coverage[bid * LL + tid];
        __syncthreads();
    }
    if (bid < 384) {
        // W repack quarter-row: ws_W[i][o][e] = bf16(attn_w[o][i][63][ e ^ ((o&7)<<3) ])
        const int i = bid >> 2;
        const int q = bid & 3;
        unsigned short* wout = (unsigned short*)(ws + WS_W) + (size_t)i * LL * HH;
#pragma unroll
        for (int k = 0; k < 12; ++k) {
            const int idx = q * 3072 + k * 256 + tid;
            const int o = idx >> 7, e = idx & 127;
            const int esrc = e ^ ((o & 7) << 3);
            float v = attn_w[(((size_t)o * LL + i) * HH + 63) * HH + esrc];
            __hip_bfloat16 h = __float2bfloat16(v);
            wout[idx] = *(unsigned short*)&h;
        }
    } else {
        // padded enc rows: ws_E[b][i][t] = enc[b][i][t-63] for t in [63,191), else 0
        const int eb = bid - 384;         // 0..127: 8 blocks per b, 12 rows each
        const int b = eb >> 3, part = eb & 7;
        float* eout = ws + WS_E + (size_t)b * LL * 256;
        const float* esrc = enc + (size_t)b * LL * HH;
#pragma unroll
        for (int k = 0; k < 12; ++k) {
            const int idx = part * 3072 + k * 256 + tid;
            const int i2 = idx >> 8, t = idx & 255;
            eout[idx] = (t >= 63 && t < 191) ? esrc[i2 * HH + (t - 63)] : 0.f;
        }
    }
    if (bid < 16) {   // dec_f / cvg_f for batch b = bid
        const int b = bid;
        if (tid < HH) {
            float acc = dec_b[tid];
            for (int k = 0; k < HH; ++k) acc += sh.p.hid[k] * dec_w[tid * HH + k];
            ws[WS_DEC + b * HH + tid] = acc;
        } else if (tid < HH + LL) {
            const int t = tid - HH;
            float a2 = cvg_b[t];
            for (int i2 = 0; i2 < LL; ++i2)
                a2 += sh.p.cov[i2] * cvg_w[((size_t)t * LL + i2) * HH + 63];
            ws[WS_CVG + b * LL + t] = a2;
        }
    }

    __threadfence();
    cg::this_grid().sync();
    __threadfence();

    // ================= phase 2: mfma (round-8 body verbatim) =================
    {
        const int kc = bid >> 4;     // 0..31
        const int b  = bid & 15;     // 0..15
        const int lane = tid & 63;
        const int wg   = tid >> 6;   // wave id 0..3 (w-split)
        const int lo   = lane & 15;
        const int hi   = lane >> 4;  // 0..3

        f32x4 acc[6][2];
#pragma unroll
        for (int a = 0; a < 6; ++a)
#pragma unroll
            for (int c = 0; c < 2; ++c) acc[a][c] = f32x4{0.f, 0.f, 0.f, 0.f};

        const short* wsrc = (const short*)(ws + WS_W);
        const float* esrc = ws + WS_E + (size_t)b * LL * 256;   // NOTE: no kc offset here

        for (int ii = 0; ii < 3; ++ii) {
            const int ig = kc * 3 + ii;   // global i row
            __syncthreads();
            {
                const short8* s8 = (const short8*)(wsrc + (size_t)ig * LL * HH);
                short8* d8 = (short8*)sh.m.A;
#pragma unroll
                for (int t = 0; t < 6; ++t) d8[tid + t * 256] = s8[tid + t * 256];
                if (tid < 64)
                    ((float4*)sh.m.E)[tid] = ((const float4*)(esrc + ig * 256))[tid];
            }
            __syncthreads();

#pragma unroll
            for (int s = 0; s < 4; ++s) {
                short8 af[6];
#pragma unroll
                for (int ot = 0; ot < 6; ++ot) {
                    const int o = ot * 16 + lo;
                    af[ot] = ((const short8*)sh.m.A)[o * 16 + (((s << 2) + hi) ^ (o & 7))];
                }
#pragma unroll
                for (int wt = 0; wt < 2; ++wt) {
                    const int t0 = s * 32 + hi * 8 + wg * 32 + wt * 16 + lo;  // <= 247
                    union { short8 s8; __hip_bfloat16 h[8]; } bf;
#pragma unroll
                    for (int j = 0; j < 8; ++j) bf.h[j] = __float2bfloat16(sh.m.E[t0 + j]);
#pragma unroll
                    for (int ot = 0; ot < 6; ++ot)
                        acc[ot][wt] = __builtin_amdgcn_mfma_f32_16x16x32_bf16(
                            af[ot], bf.s8, acc[ot][wt], 0, 0, 0);
                }
            }
        }

        // fp16 partial store, [kc][b][o][w], w lane-consecutive -> coalesced
        __half* dst = (__half*)(ws + WS_P) + (size_t)(kc * BB + b) * LL * HH;
#pragma unroll
        for (int ot = 0; ot < 6; ++ot)
#pragma unroll
            for (int wt = 0; wt < 2; ++wt)
#pragma unroll
                for (int r = 0; r < 4; ++r) {
                    const int o = ot * 16 + hi * 4 + r;
                    const int w = wg * 32 + wt * 16 + lo;
                    dst[o * HH + w] = __float2half(acc[ot][wt][r]);
                }
    }

    __threadfence();
    cg::this_grid().sync();
    __threadfence();

    // ================= phase 3: reduce (3 (o,b) pairs per block) =================
    for (int j = 0; j < 3; ++j) {
        const int pr = bid * 3 + j;       // 0..1535
        const int o  = pr % LL;
        const int b2 = pr / LL;
        float s = 0.f;
        if (tid < 128) {
            const __half* pp = (const __half*)(ws + WS_P) + ((size_t)b2 * LL + o) * HH + tid;
            float sum = 0.f;
#pragma unroll
            for (int kc = 0; kc < 32; ++kc)
                sum += __half2float(pp[(size_t)kc * BB * LL * HH]);
            float ef = sum + attn_b[o] + ws[WS_DEC + b2 * HH + tid] + ws[WS_CVG + b2 * LL + o];
            s = tanhf(ef) * vvec[b2 * HH + tid];
#pragma unroll
            for (int off = 32; off > 0; off >>= 1) s += __shfl_down(s, off, 64);
        }
        if (tid < 128 && (tid & 63) == 0) sh.r.r2[tid >> 6] = s;
        __syncthreads();
        if (tid == 0) ws[WS_SC + b2 * LL + o] = sh.r.r2[0] + sh.r.r2[1];
        __syncthreads();
    }

    __threadfence();
    cg::this_grid().sync();
    __threadfence();

    // ================= phase 4: softmax + outputs (blocks 0..15) =================
    if (bid >= 16) return;
    {
        const int b = bid;
        const int t = tid;
        if (t < LL) sh.f.sc[t] = ws[WS_SC + b * LL + t];
        __syncthreads();

        float mx = -1e30f;
        for (int l = 0; l < LL; ++l) mx = fmaxf(mx, sh.f.sc[l]);
        float sum = 0.f;
        for (int l = 0; l < LL; ++l) sum += expf(sh.f.sc[l] - mx);

        if (t < LL) {
            float a = expf(sh.f.sc[t] - mx) / sum;
            sh.f.at[t] = a;
            out[BB * HH + b * LL + t] = a;                                   // attn
            out[BB * HH + BB * LL + b * LL + t] = coverage[b * LL + t] + a;  // new_coverage
        }
        __syncthreads();

        if (t < HH) {
            float ctx = 0.f;
#pragma unroll 8
            for (int l = 0; l < LL; ++l) ctx += sh.f.at[l] * enc[((size_t)b * LL + l) * HH + t];
            out[b * HH + t] = ctx;                                           // context
        }
    }
}

extern "C" void kernel_launch(void* const* d_in, const int* in_sizes, int n_in,
                              void* d_out, int out_size, void* d_ws, size_t ws_size,
                              hipStream_t stream) {
    const float* hidden   = (const float*)d_in[0];
    const float* enc      = (const float*)d_in[1];
    const float* coverage = (const float*)d_in[2];
    const float* attn_w   = (const float*)d_in[3];
    const float* attn_b   = (const float*)d_in[4];
    const float* cvg_w    = (const float*)d_in[5];
    const float* cvg_b    = (const float*)d_in[6];
    const float* dec_w    = (const float*)d_in[7];
    const float* dec_b    = (const float*)d_in[8];
    const float* vvec     = (const float*)d_in[9];
    float* out = (float*)d_out;
    float* ws  = (float*)d_ws;

    void* args[] = {
        (void*)&hidden, (void*)&enc, (void*)&coverage, (void*)&attn_w,
        (void*)&attn_b, (void*)&cvg_w, (void*)&cvg_b, (void*)&dec_w,
        (void*)&dec_b, (void*)&vvec, (void*)&ws, (void*)&out,
    };
    hipLaunchCooperativeKernel((void*)fused_kernel, dim3(512), dim3(256),
                               args, 0, stream);
}

// Round 10
// 49.787 us; speedup vs baseline: 9.3129x; 9.3129x over previous
//
#include <hip/hip_runtime.h>
#include <hip/hip_bf16.h>
#include <hip/hip_fp16.h>
#include <math.h>

// Problem constants: B=16, L=96, H=128.
#define BB 16
#define LL 96
#define HH 128

typedef __attribute__((ext_vector_type(8))) short short8;
typedef __attribute__((ext_vector_type(4))) float f32x4;

// Only slice kh=63 of attn_conv_w matters (input height 1, SAME pad (63,64)).
// Only slice kw=63 of cvg_conv_w matters (input width 1, SAME pad (63,64)).
//
// ws layout (float units) — round-8 offsets kept; WS_W/WS_E regions now unused:
#define WS_DEC  983040         // 16*128 fp32
#define WS_CVG  985088         // 16*96  fp32
#define WS_SC   986624         // 16*96  fp32
#define WS_P    988160         // fp16 partials [kc][b][o][w]: 32*16*96*128 halves

// ---------------- M: mfma with embedded prep (W/E staged straight from inputs) -------------
// grid (kc=32, b=16); 256 threads = 4 w-split waves. Per block: 3 i-rows, K=384.
// Linear block id = kc + 32*b; 32 % 8 == 0 -> all 16 b-blocks of one kc share an XCD
// (L2-local W fan-out), no swizzle needed.
__global__ __launch_bounds__(256) void mfma_kernel(
        const float* __restrict__ hidden,
        const float* __restrict__ enc,
        const float* __restrict__ coverage,
        const float* __restrict__ attn_w,
        const float* __restrict__ cvg_w,
        const float* __restrict__ cvg_b,
        const float* __restrict__ dec_w,
        const float* __restrict__ dec_b,
        float* __restrict__ ws) {
    const int kc = blockIdx.x;   // 0..31
    const int b  = blockIdx.y;   // 0..15
    const int tid  = threadIdx.x;
    const int lane = tid & 63;
    const int wg   = tid >> 6;   // wave id 0..3 (w-split)
    const int lo   = lane & 15;
    const int hi   = lane >> 4;  // 0..3

    __shared__ __align__(16) short Abuf[LL * HH];  // 24KB bf16 W[o][e] (e swizzled)
    __shared__ __align__(16) float Ebuf[256];      // zero-padded enc row (fp32)

    f32x4 acc[6][2];
#pragma unroll
    for (int a = 0; a < 6; ++a)
#pragma unroll
        for (int c = 0; c < 2; ++c) acc[a][c] = f32x4{0.f, 0.f, 0.f, 0.f};

    for (int ii = 0; ii < 3; ++ii) {
        const int ig = kc * 3 + ii;   // global i row
        __syncthreads();
        // stage A directly from attn_w: dst octet (o,a) <- src octet (a ^ (o&7)),
        // fp32 -> bf16 convert in flight. 1536 octets, 6 per thread.
#pragma unroll
        for (int t = 0; t < 6; ++t) {
            const int oct = tid + t * 256;
            const int o = oct >> 4, a = oct & 15;
            const int asrc = a ^ (o & 7);
            const float* src = attn_w + (((size_t)o * LL + ig) * HH + 63) * HH + asrc * 8;
            float4 f0 = *(const float4*)(src);
            float4 f1 = *(const float4*)(src + 4);
            union { unsigned short us[8]; short8 s8; } pk;
            const float fv[8] = {f0.x, f0.y, f0.z, f0.w, f1.x, f1.y, f1.z, f1.w};
#pragma unroll
            for (int j = 0; j < 8; ++j) {
                __hip_bfloat16 h = __float2bfloat16(fv[j]);
                pk.us[j] = *(unsigned short*)&h;
            }
            ((short8*)Abuf)[oct] = pk.s8;
        }
        // stage E row directly from enc (zero-padded window)
        {
            float v = 0.f;
            if (tid >= 63 && tid < 191) v = enc[((size_t)b * LL + ig) * HH + (tid - 63)];
            Ebuf[tid] = v;
        }
        __syncthreads();

#pragma unroll
        for (int s = 0; s < 4; ++s) {      // k-step within i (m0 = 32s)
            short8 af[6];
#pragma unroll
            for (int ot = 0; ot < 6; ++ot) {
                const int o = ot * 16 + lo;
                const int idx8 = o * 16 + (((s << 2) + hi) ^ (o & 7));
                af[ot] = ((const short8*)Abuf)[idx8];
            }
#pragma unroll
            for (int wt = 0; wt < 2; ++wt) {
                const int t0 = s * 32 + hi * 8 + wg * 32 + wt * 16 + lo;  // <= 247
                union { short8 s8; __hip_bfloat16 h[8]; } bf;
#pragma unroll
                for (int j = 0; j < 8; ++j) bf.h[j] = __float2bfloat16(Ebuf[t0 + j]);
#pragma unroll
                for (int ot = 0; ot < 6; ++ot)
                    acc[ot][wt] = __builtin_amdgcn_mfma_f32_16x16x32_bf16(
                        af[ot], bf.s8, acc[ot][wt], 0, 0, 0);
            }
        }
    }

    // write split-K partials (fp16, [kc][b][o][w], w lane-consecutive -> coalesced)
    __half* dst = (__half*)(ws + WS_P) + (size_t)(kc * BB + b) * LL * HH;
#pragma unroll
    for (int ot = 0; ot < 6; ++ot)
#pragma unroll
        for (int wt = 0; wt < 2; ++wt)
#pragma unroll
            for (int r = 0; r < 4; ++r) {
                const int o = ot * 16 + hi * 4 + r;     // C/D: row=(lane>>4)*4+reg
                const int w = wg * 32 + wt * 16 + lo;   //      col=lane&15
                dst[o * HH + w] = __float2half(acc[ot][wt][r]);
            }

    // kc==0 blocks additionally compute dec_f / cvg_f (read by reduce kernel next launch)
    if (kc == 0) {
        if (tid < HH) {
            float acc2 = dec_b[tid];
            for (int k = 0; k < HH; ++k)
                acc2 += hidden[b * HH + k] * dec_w[tid * HH + k];
            ws[WS_DEC + b * HH + tid] = acc2;
        } else if (tid < HH + LL) {
            const int t = tid - HH;
            float a2 = cvg_b[t];
            for (int i2 = 0; i2 < LL; ++i2)
                a2 += coverage[b * LL + i2] * cvg_w[((size_t)t * LL + i2) * HH + 63];
            ws[WS_CVG + b * LL + t] = a2;
        }
    }
}

// ---------------- R: sum partials + bias/dec/cvg -> tanh -> dot v -> scores ----------------
__global__ __launch_bounds__(128) void reduce_kernel(
        const float* __restrict__ attn_b,
        const float* __restrict__ vvec,
        float* __restrict__ ws) {
    const int o = blockIdx.x;   // 0..95
    const int b = blockIdx.y;   // 0..15
    const int h = threadIdx.x;  // 0..127
    const __half* p = (const __half*)(ws + WS_P) + ((size_t)b * LL + o) * HH + h;
    float sum = 0.f;
#pragma unroll
    for (int kc = 0; kc < 32; ++kc)
        sum += __half2float(p[(size_t)kc * BB * LL * HH]);
    float ef = sum + attn_b[o] + ws[WS_DEC + b * HH + h] + ws[WS_CVG + b * LL + o];
    float s = tanhf(ef) * vvec[b * HH + h];
#pragma unroll
    for (int off = 32; off > 0; off >>= 1) s += __shfl_down(s, off, 64);
    __shared__ float r2[2];
    if ((h & 63) == 0) r2[h >> 6] = s;
    __syncthreads();
    if (h == 0) ws[WS_SC + b * LL + o] = r2[0] + r2[1];
}

// ---------------- F: softmax + outputs ----------------
__global__ void finalize_kernel(const float* __restrict__ ws_scores,
                                const float* __restrict__ coverage,
                                const float* __restrict__ enc,
                                float* __restrict__ out) {
    int b = blockIdx.x;
    int t = threadIdx.x;  // 0..127
    __shared__ float sc[LL];
    __shared__ float at[LL];
    if (t < LL) sc[t] = ws_scores[b * LL + t];
    __syncthreads();

    float mx = -1e30f;
    for (int l = 0; l < LL; ++l) mx = fmaxf(mx, sc[l]);
    float sum = 0.f;
    for (int l = 0; l < LL; ++l) sum += expf(sc[l] - mx);

    if (t < LL) {
        float a = expf(sc[t] - mx) / sum;
        at[t] = a;
        out[BB * HH + b * LL + t] = a;                                   // attn
        out[BB * HH + BB * LL + b * LL + t] = coverage[b * LL + t] + a;  // new_coverage
    }
    __syncthreads();

    float ctx = 0.f;
#pragma unroll 8
    for (int l = 0; l < LL; ++l) ctx += at[l] * enc[((size_t)b * LL + l) * HH + t];
    out[b * HH + t] = ctx;                                               // context
}

extern "C" void kernel_launch(void* const* d_in, const int* in_sizes, int n_in,
                              void* d_out, int out_size, void* d_ws, size_t ws_size,
                              hipStream_t stream) {
    const float* hidden   = (const float*)d_in[0];
    const float* enc      = (const float*)d_in[1];
    const float* coverage = (const float*)d_in[2];
    const float* attn_w   = (const float*)d_in[3];
    const float* attn_b   = (const float*)d_in[4];
    const float* cvg_w    = (const float*)d_in[5];
    const float* cvg_b    = (const float*)d_in[6];
    const float* dec_w    = (const float*)d_in[7];
    const float* dec_b    = (const float*)d_in[8];
    const float* vvec     = (const float*)d_in[9];
    float* out = (float*)d_out;
    float* ws  = (float*)d_ws;

    mfma_kernel<<<dim3(32, BB), 256, 0, stream>>>(hidden, enc, coverage, attn_w,
                                                  cvg_w, cvg_b, dec_w, dec_b, ws);
    reduce_kernel<<<dim3(LL, BB), 128, 0, stream>>>(attn_b, vvec, ws);
    finalize_kernel<<<BB, HH, 0, stream>>>(ws + WS_SC, coverage, enc, out);
}